// Round 9
// baseline (262.966 us; speedup 1.0000x reference)
//
#include <hip/hip_runtime.h>
#include <hip/hip_bf16.h>

// Problem constants
#define NB 16
#define ND 512
#define NT 2048
#define TM1 2047
#define NHD 256

typedef __attribute__((ext_vector_type(8))) short bf16x8;
typedef __attribute__((ext_vector_type(4))) float f32x4;
typedef unsigned short ushort_t;
typedef unsigned int uint_t;

// ws layout (float offsets): r0acc/sxacc zeroed by hipMemsetAsync.
#define G0_OFF    0ull                     // (unused; g0 eliminated in r9)
#define R0_OFF    32768ull                 // r0acc [16][512]
#define SX_OFF    40960ull                 // sxacc [16][512]
#define WSUM_OFF  49152ull
#define WKQT_OFF  49408ull                 // 512*512 bf16 = 131072 floats
#define CHUNK_OFF 180480ull
#define BATCH_US  (2048ull * 512ull)       // ushorts per batch per array (2 MB)
#define BATCH_FLOATS (2ull * 524288ull)    // qdb + xst floats per batch (4 MB)

__device__ __forceinline__ ushort_t f2bf(float x) {
    union { float f; uint_t u; } v; v.f = x;
    uint_t r = v.u + 0x7FFFu + ((v.u >> 16) & 1u);  // round-to-nearest-even
    return (ushort_t)(r >> 16);
}
__device__ __forceinline__ float bf2f(uint_t u) {
    union { uint_t u; float f; } v; v.u = u << 16;
    return v.f;
}

// Async global->LDS DMA, 16 B/lane, 1024 B/wave-instruction.
__device__ __forceinline__ void async_copy16(const ushort_t* g, ushort_t* l) {
    __builtin_amdgcn_global_load_lds(
        (const __attribute__((address_space(1))) void*)g,
        (__attribute__((address_space(3))) void*)l, 16, 0, 0);
}

#define FENCE() asm volatile("" ::: "memory")
#define BARRIER() do { FENCE(); __builtin_amdgcn_s_barrier(); FENCE(); } while (0)
#define WAITVM4() asm volatile("s_waitcnt vmcnt(4)" ::: "memory")
#define WAITVM0() asm volatile("s_waitcnt vmcnt(0)" ::: "memory")

// --- xst[c][t][d] = bf16(xs[b0+c][d][t]);  + sxacc;  + one-time prep -----
// sxacc[b,d] += sum_t xs[b,d,t] (t != 2047), accumulated from the fp32
// tile (linear in t -> per-block partials via atomics, no sync needed).
// Prep folded in (cc==0,b0==0): wkqT = bf16(wkq^T), wsum = sum(wlast).
__global__ __launch_bounds__(256) void k_cvt_xst(const float* __restrict__ xs,
                                                 ushort_t* __restrict__ xst, int b0,
                                                 const float* __restrict__ wkq,
                                                 ushort_t* __restrict__ wkqT,
                                                 const float* __restrict__ wlast,
                                                 float* __restrict__ wsum,
                                                 float* __restrict__ sxacc) {
    __shared__ float tile[64][257];
    __shared__ float sxl[64];
    const int t0 = blockIdx.x * 256, d0 = blockIdx.y * 64;
    const int cc = blockIdx.z;
    const float* xb = xs + (size_t)(b0 + cc) * ND * NT;
    ushort_t* xo = xst + (size_t)cc * BATCH_US;
    const int wave = threadIdx.x >> 6, lane = threadIdx.x & 63;
    if (threadIdx.x < 64) sxl[threadIdx.x] = 0.f;
    #pragma unroll
    for (int i = 0; i < 16; ++i) {
        const int row = wave * 16 + i;
        *(float4*)&tile[row][lane * 4] =
            *(const float4*)&xb[(size_t)(d0 + row) * NT + t0 + lane * 4];
    }
    __syncthreads();
    const int c8 = (threadIdx.x & 7) * 8;
    float sxp[8] = {0.f, 0.f, 0.f, 0.f, 0.f, 0.f, 0.f, 0.f};
    #pragma unroll
    for (int i = 0; i < 8; ++i) {
        const int t = i * 32 + (threadIdx.x >> 3);
        uint_t w[4];
        #pragma unroll
        for (int p = 0; p < 4; ++p)
            w[p] = (uint_t)f2bf(tile[c8 + 2 * p][t]) |
                   ((uint_t)f2bf(tile[c8 + 2 * p + 1][t]) << 16);
        *(uint4*)&xo[(size_t)(t0 + t) * ND + d0 + c8] = *(uint4*)w;
        if (t0 + t != 2047) {
            #pragma unroll
            for (int p = 0; p < 8; ++p) sxp[p] += tile[c8 + p][t];
        }
    }
    #pragma unroll
    for (int p = 0; p < 8; ++p) atomicAdd(&sxl[c8 + p], sxp[p]);
    __syncthreads();
    if (threadIdx.x < 64)
        atomicAdd(&sxacc[(size_t)(b0 + cc) * ND + d0 + threadIdx.x], sxl[threadIdx.x]);
    // ---- prep (once, on the cc==0 plane of the first chunk) ----
    if (cc == 0 && b0 == 0) {
        __shared__ float ptile[32][33];
        const int bid = blockIdx.y * 8 + blockIdx.x;   // 0..63
        const int c = threadIdx.x & 31, r = threadIdx.x >> 5;  // r in 0..7
        #pragma unroll 1
        for (int q = 0; q < 4; ++q) {
            const int job = bid * 4 + q;               // 0..255
            const int j0 = (job & 15) * 32, dd0 = (job >> 4) * 32;
            __syncthreads();
            #pragma unroll
            for (int i = 0; i < 4; ++i)
                ptile[r + i * 8][c] = wkq[(size_t)(dd0 + r + i * 8) * ND + j0 + c];
            __syncthreads();
            #pragma unroll
            for (int i = 0; i < 4; ++i)
                wkqT[(size_t)(j0 + r + i * 8) * ND + dd0 + c] = f2bf(ptile[c][r + i * 8]);
        }
        if (bid == 0) {
            __shared__ float red[256];
            float s = 0.f;
            for (int t = threadIdx.x; t < NT; t += 256) s += wlast[t];
            red[threadIdx.x] = s;
            __syncthreads();
            for (int off = 128; off > 0; off >>= 1) {
                if (threadIdx.x < off) red[threadIdx.x] += red[threadIdx.x + off];
                __syncthreads();
            }
            if (threadIdx.x == 0) *wsum = red[0];
        }
    }
}

// === helpers for the 256x256 BK=64 8-phase core (k_qd, r2-validated) =====
__device__ __forceinline__ void ld_frag4(bf16x8 (&dst)[4][2], const ushort_t* buf,
                                         int rbase, int l15, int quad, int swz) {
    #pragma unroll
    for (int i = 0; i < 4; ++i)
        #pragma unroll
        for (int kc = 0; kc < 2; ++kc)
            dst[i][kc] = *(const bf16x8*)&buf[(rbase + i * 16 + l15) * 64 + (((kc * 4 + quad) ^ swz) << 3)];
}
__device__ __forceinline__ void ld_frag2(bf16x8 (&dst)[2][2], const ushort_t* buf,
                                         int rbase, int l15, int quad, int swz) {
    #pragma unroll
    for (int i = 0; i < 2; ++i)
        #pragma unroll
        for (int kc = 0; kc < 2; ++kc)
            dst[i][kc] = *(const bf16x8*)&buf[(rbase + i * 16 + l15) * 64 + (((kc * 4 + quad) ^ swz) << 3)];
}
__device__ __forceinline__ void mfma8(f32x4 (&acc)[8][4], const bf16x8 (&a)[4][2],
                                      const bf16x8 (&bb)[2][2], int mbase, int nbase) {
    __builtin_amdgcn_s_setprio(1);
    #pragma unroll
    for (int kc = 0; kc < 2; ++kc)
        #pragma unroll
        for (int mi = 0; mi < 4; ++mi)
            #pragma unroll
            for (int nj = 0; nj < 2; ++nj)
                acc[mbase + mi][nbase + nj] = __builtin_amdgcn_mfma_f32_16x16x32_bf16(
                    a[mi][kc], bb[nj][kc], acc[mbase + mi][nbase + nj], 0, 0, 0);
    __builtin_amdgcn_s_setprio(0);
}

__device__ __forceinline__ void gemm8ph(const ushort_t* __restrict__ Ag,
                                        const ushort_t* __restrict__ Bg,
                                        ushort_t* __restrict__ smA0, ushort_t* __restrict__ smA1,
                                        ushort_t* __restrict__ smB0, ushort_t* __restrict__ smB1,
                                        f32x4 (&acc)[8][4]) {
    const int tid = threadIdx.x;
    const int wave = tid >> 6, lane = tid & 63;
    const int l15 = lane & 15, quad = lane >> 4;
    const int wm = wave >> 2;                      // 2 (M) x 4 (N) waves
    const int swz = l15 & 7;
    const int lrow = lane >> 3;
    const size_t lsrc = (size_t)lrow * ND + (size_t)(((lane & 7) ^ lrow) << 3);
    ushort_t* smA[2] = {smA0, smA1};
    ushort_t* smB[2] = {smB0, smB1};

#define STAGE(gb_, buf_, kt_, h_) do {                                        \
        const ushort_t* g_ = (gb_) + (size_t)((h_) * 128 + wave * 8) * ND +   \
                             (kt_) * 64 + lsrc;                               \
        ushort_t* l_ = (buf_) + (h_) * 8192 + wave * 512;                     \
        async_copy16(g_, l_);                                                 \
        async_copy16(g_ + (size_t)64 * ND, l_ + 4096);                        \
    } while (0)

    bf16x8 a[4][2], br[2][2][2];

    STAGE(Bg, smB[0], 0, 0); STAGE(Bg, smB[0], 0, 1);
    STAGE(Ag, smA[0], 0, 0); STAGE(Ag, smA[0], 0, 1);
    STAGE(Bg, smB[1], 1, 0); STAGE(Bg, smB[1], 1, 1);
    WAITVM4();
    BARRIER();

    #pragma unroll
    for (int j = 0; j < 4; ++j) {
        const int kO = 2 * j + 1;
        ld_frag4(a, smA[0], wm * 128, l15, quad, swz);
        ld_frag2(br[0], smB[0], (wave & 3) * 64, l15, quad, swz);
        STAGE(Ag, smA[1], kO, 0);
        BARRIER();
        mfma8(acc, a, br[0], 0, 0);
        BARRIER();
        ld_frag2(br[1], smB[0], (wave & 3) * 64 + 32, l15, quad, swz);
        STAGE(Ag, smA[1], kO, 1);
        BARRIER();
        mfma8(acc, a, br[1], 0, 2);
        BARRIER();
        ld_frag4(a, smA[0], wm * 128 + 64, l15, quad, swz);
        if (j < 3) STAGE(Bg, smB[0], 2 * j + 2, 0);
        BARRIER();
        mfma8(acc, a, br[0], 4, 0);
        BARRIER();
        if (j < 3) STAGE(Bg, smB[0], 2 * j + 2, 1);
        BARRIER();
        mfma8(acc, a, br[1], 4, 2);
        if (j < 3) { WAITVM4(); } else { WAITVM0(); }
        BARRIER();
        ld_frag4(a, smA[1], wm * 128, l15, quad, swz);
        ld_frag2(br[0], smB[1], (wave & 3) * 64, l15, quad, swz);
        if (j < 3) STAGE(Ag, smA[0], 2 * j + 2, 0);
        BARRIER();
        mfma8(acc, a, br[0], 0, 0);
        BARRIER();
        ld_frag2(br[1], smB[1], (wave & 3) * 64 + 32, l15, quad, swz);
        if (j < 3) STAGE(Ag, smA[0], 2 * j + 2, 1);
        BARRIER();
        mfma8(acc, a, br[1], 0, 2);
        BARRIER();
        ld_frag4(a, smA[1], wm * 128 + 64, l15, quad, swz);
        if (j < 3) STAGE(Bg, smB[1], kO + 2, 0);
        BARRIER();
        mfma8(acc, a, br[0], 4, 0);
        BARRIER();
        if (j < 3) STAGE(Bg, smB[1], kO + 2, 1);
        BARRIER();
        mfma8(acc, a, br[1], 4, 2);
        if (j < 3) WAITVM4();
        BARRIER();
    }
#undef STAGE
}

// --- qdb[c][s][j] = bf16( sign_j * sum_d xst[c][s][d] * wkqT[j][d] ) -----
__global__ __launch_bounds__(512, 2) void k_qd(const ushort_t* __restrict__ xst,
                                               const ushort_t* __restrict__ wkqT,
                                               ushort_t* __restrict__ qdb) {
    __shared__ __align__(16) ushort_t smA[2][16384];
    __shared__ __align__(16) ushort_t smB[2][16384];
    const int lin = blockIdx.x + gridDim.x * (blockIdx.y + gridDim.y * blockIdx.z);
    const int nwg8 = (gridDim.x * gridDim.y * gridDim.z) >> 3;
    const int logical = (lin & 7) * nwg8 + (lin >> 3);
    const int jt = logical & 1;
    const int st = (logical >> 1) & 7;
    const int cc = logical >> 4;
    const int j0 = jt * 256, s0 = st * 256;

    const ushort_t* Ag = xst + (size_t)cc * BATCH_US + (size_t)s0 * ND;
    const ushort_t* Bg = wkqT + (size_t)j0 * ND;
    ushort_t* qo = qdb + (size_t)cc * BATCH_US;

    f32x4 acc[8][4];
    #pragma unroll
    for (int mi = 0; mi < 8; ++mi)
        #pragma unroll
        for (int nj = 0; nj < 4; ++nj) acc[mi][nj] = (f32x4){0.f, 0.f, 0.f, 0.f};

    gemm8ph(Ag, Bg, smA[0], smA[1], smB[0], smB[1], acc);

    const int tid = threadIdx.x;
    const int wave = tid >> 6, lane = tid & 63;
    const int l15 = lane & 15, quad = lane >> 4;
    const int wm = wave >> 2, wn = wave & 3;
    const float sgn = (j0 == 0) ? 1.f : -1.f;      // j>=256 is head-1 (negated)
    #pragma unroll
    for (int mi = 0; mi < 8; ++mi) {
        const int srow = s0 + wm * 128 + mi * 16 + quad * 4;
        #pragma unroll
        for (int nj = 0; nj < 4; ++nj) {
            const int jcol = j0 + wn * 64 + nj * 16 + l15;
            #pragma unroll
            for (int r = 0; r < 4; ++r)
                qo[(size_t)(srow + r) * ND + jcol] = f2bf(sgn * acc[mi][nj][r]);
        }
    }
}

// --- k_attn: r8 4-block/CU m97 loop + fused r0acc fold (k_r eliminated) --
// Per block (st, tq, cc): Delta over s-tile(128) x t-quarter(512), K=512;
// sigmoid-weighted sums accumulate in gp registers across t-tiles (one
// shfl-reduce at the end); then the block folds its PARTIAL g into
// r0acc[b,d] += sum_s x[s,d]*g_partial[s]  (linear in g -> atomicAdd,
// no cross-block ordering).  g0 has no consumer and is gone.
__global__ __launch_bounds__(256, 4) void k_attn(const ushort_t* __restrict__ qdb,
                                                 const ushort_t* __restrict__ xst,
                                                 const float* __restrict__ wlast,
                                                 float* __restrict__ r0acc, int b0) {
    __shared__ __align__(16) ushort_t smA[8192];   // 128 x 64
    __shared__ __align__(16) ushort_t smB[8192];   // 128 x 64
    __shared__ float lds_g[128];
    const int lin = blockIdx.x + gridDim.x * (blockIdx.y + gridDim.y * blockIdx.z);
    const int nwg8 = (gridDim.x * gridDim.y * gridDim.z) >> 3;
    const int logical = (lin & 7) * nwg8 + (lin >> 3);
    const int st = logical & 15;
    const int tq = (logical >> 4) & 3;
    const int cc = logical >> 6;
    const int s0 = st * 128;
    const int b = b0 + cc;

    const int tid = threadIdx.x;
    const int wave = tid >> 6, lane = tid & 63;
    const int l15 = lane & 15, quad = lane >> 4;
    const int wm = wave >> 1, wn = wave & 1;       // 2 (M) x 2 (N)
    const int swz = l15 & 7;
    const int lrow = lane >> 3;
    const size_t lsrc = (size_t)lrow * ND + (size_t)(((lane & 7) ^ lrow) << 3);
    const ushort_t* Ag = qdb + (size_t)cc * BATCH_US + (size_t)s0 * ND;
    const ushort_t* Bg = xst + (size_t)cc * BATCH_US + (size_t)(tq * 512) * ND;

#define STAGEA(kt_) do {                                                      \
        const size_t ko_ = (size_t)(kt_) * 64;                                \
        _Pragma("unroll")                                                     \
        for (int n_ = 0; n_ < 4; ++n_) {                                      \
            const int rb_ = wave * 32 + n_ * 8;                               \
            async_copy16(Ag + (size_t)rb_ * ND + ko_ + lsrc, smA + rb_ * 64); \
        }                                                                     \
    } while (0)
#define STAGEB(kt_, tt_) do {                                                 \
        const size_t ko_ = (size_t)(kt_) * 64;                                \
        const size_t ro_ = (size_t)(tt_) * 128;                               \
        _Pragma("unroll")                                                     \
        for (int n_ = 0; n_ < 4; ++n_) {                                      \
            const int rb_ = wave * 32 + n_ * 8;                               \
            async_copy16(Bg + (ro_ + rb_) * ND + ko_ + lsrc, smB + rb_ * 64); \
        }                                                                     \
    } while (0)
#define COMPUTE() do {                                                        \
        _Pragma("unroll")                                                     \
        for (int kc = 0; kc < 2; ++kc) {                                      \
            bf16x8 af_[4], bf_[4];                                            \
            _Pragma("unroll")                                                 \
            for (int mi = 0; mi < 4; ++mi)                                    \
                af_[mi] = *(const bf16x8*)&smA[(wm * 64 + mi * 16 + l15) * 64 \
                          + (((kc * 4 + quad) ^ swz) << 3)];                  \
            _Pragma("unroll")                                                 \
            for (int nj = 0; nj < 4; ++nj)                                    \
                bf_[nj] = *(const bf16x8*)&smB[(wn * 64 + nj * 16 + l15) * 64 \
                          + (((kc * 4 + quad) ^ swz) << 3)];                  \
            __builtin_amdgcn_s_setprio(1);                                    \
            _Pragma("unroll")                                                 \
            for (int mi = 0; mi < 4; ++mi)                                    \
                _Pragma("unroll")                                             \
                for (int nj = 0; nj < 4; ++nj)                                \
                    acc[mi][nj] = __builtin_amdgcn_mfma_f32_16x16x32_bf16(    \
                        af_[mi], bf_[nj], acc[mi][nj], 0, 0, 0);              \
            __builtin_amdgcn_s_setprio(0);                                    \
        }                                                                     \
    } while (0)

    f32x4 acc[4][4];
    float gp[4][4];
    #pragma unroll
    for (int mi = 0; mi < 4; ++mi)
        #pragma unroll
        for (int nj = 0; nj < 4; ++nj) { acc[mi][nj] = (f32x4){0.f, 0.f, 0.f, 0.f}; gp[mi][nj] = 0.f; }
    if (tid < 128) lds_g[tid] = 0.f;

    // iters: kt = it&7 (K-tile), tt = it>>3 (t-tile within quarter).
    #pragma unroll 1
    for (int it = 0; it < 32; ++it) {
        const int kt = it & 7, tt = it >> 3;
        STAGEA(kt);
        STAGEB(kt, tt);
        WAITVM0();
        BARRIER();
        COMPUTE();
        // K complete for this t-tile: sigmoid into gp registers (no sync).
        if (kt == 7) {
            const int tb = tq * 512 + tt * 128;
            float wt[4];
            #pragma unroll
            for (int nj = 0; nj < 4; ++nj) wt[nj] = wlast[tb + wn * 64 + nj * 16 + l15];
            #pragma unroll
            for (int mi = 0; mi < 4; ++mi)
                #pragma unroll
                for (int r = 0; r < 4; ++r) {
                    #pragma unroll
                    for (int nj = 0; nj < 4; ++nj) {
                        const float e = __expf(-acc[mi][nj][r]);
                        gp[mi][r] = fmaf(__builtin_amdgcn_rcpf(1.f + e), wt[nj], gp[mi][r]);
                    }
                }
            #pragma unroll
            for (int mi = 0; mi < 4; ++mi)
                #pragma unroll
                for (int nj = 0; nj < 4; ++nj) acc[mi][nj] = (f32x4){0.f, 0.f, 0.f, 0.f};
        }
        BARRIER();   // WAR: all ds_reads done before next stage overwrites
    }
#undef STAGEA
#undef STAGEB
#undef COMPUTE

    // single reduce of gp -> lds_g (partial g for this t-quarter)
    #pragma unroll
    for (int mi = 0; mi < 4; ++mi)
        #pragma unroll
        for (int r = 0; r < 4; ++r) {
            float v = gp[mi][r];
            v += __shfl_xor(v, 1);
            v += __shfl_xor(v, 2);
            v += __shfl_xor(v, 4);
            v += __shfl_xor(v, 8);
            if (l15 == 0) atomicAdd(&lds_g[wm * 64 + mi * 16 + quad * 4 + r], v);
        }
    __syncthreads();
    // fold partial g into r0acc: r0[b,d] += sum_s x[s,d] * g_partial[s]
    {
        const ushort_t* xrow = xst + (size_t)cc * BATCH_US + (size_t)s0 * ND;
        const int send = (st == 15) ? 127 : 128;   // exclude s = 2047
        float a0 = 0.f, a1 = 0.f;
        for (int si = 0; si < send; ++si) {
            const float gv = lds_g[si];
            const uint_t pk = *(const uint_t*)&xrow[(size_t)si * ND + tid * 2];
            a0 = fmaf(bf2f(pk & 0xFFFFu), gv, a0);
            a1 = fmaf(bf2f(pk >> 16), gv, a1);
        }
        atomicAdd(&r0acc[(size_t)b * ND + tid * 2], a0);
        atomicAdd(&r0acc[(size_t)b * ND + tid * 2 + 1], a1);
    }
}

// --- out[b,i] = sum_d W_PV[i,d] * r[b, i/256, d]  (fp32 out) -------------
__global__ __launch_bounds__(256) void k_out(const float* __restrict__ wpv,
                                             const float* __restrict__ r0acc,
                                             const float* __restrict__ sxacc,
                                             const float* __restrict__ wsum,
                                             float* __restrict__ out) {
    const int b = blockIdx.x;
    const int i0 = blockIdx.y * 256;
    __shared__ float rs[1024];
    const float wsv = *wsum;
    for (int i = threadIdx.x; i < ND; i += 256) {
        const float r0 = r0acc[b * ND + i];
        const float sx = sxacc[b * ND + i];
        rs[i] = r0;                        // head 0
        rs[ND + i] = fmaf(wsv, sx, -r0);   // head 1
    }
    __syncthreads();
    const int i = i0 + threadIdx.x;
    const float* wrow = wpv + (size_t)i * ND;
    const float* rh = rs + (i >> 8) * ND;
    float acc = 0.f;
    for (int dd = 0; dd < ND; dd += 4) {
        const float4 wv = *(const float4*)(wrow + dd);
        acc += wv.x * rh[dd] + wv.y * rh[dd + 1] + wv.z * rh[dd + 2] + wv.w * rh[dd + 3];
    }
    out[b * ND + i] = acc;
}

extern "C" void kernel_launch(void* const* d_in, const int* in_sizes, int n_in,
                              void* d_out, int out_size, void* d_ws, size_t ws_size,
                              hipStream_t stream) {
    (void)in_sizes; (void)n_in; (void)out_size;
    const float* xs   = (const float*)d_in[0];
    const float* wkq  = (const float*)d_in[1];
    const float* wpv  = (const float*)d_in[2];
    const float* wout = (const float*)d_in[3];
    const float* wlast = wout + (size_t)(NT - 1) * NT;  // W_out[-1]

    float* ws    = (float*)d_ws;
    float* r0acc = ws + R0_OFF;
    float* sxacc = ws + SX_OFF;
    float* wsum  = ws + WSUM_OFF;
    ushort_t* wkqT = (ushort_t*)(ws + WKQT_OFF);

    // Chunk batches: per batch needs 2 MB qdb + 2 MB xst of ws.
    const size_t ws_floats = ws_size / 4;
    size_t avail = (ws_floats > CHUNK_OFF) ? (ws_floats - CHUNK_OFF) : 0;
    int C = (int)(avail / BATCH_FLOATS);
    if (C > NB) C = NB;
    if (C < 1) C = 1;
    ushort_t* qdb = (ushort_t*)(ws + CHUNK_OFF);
    ushort_t* xst = (ushort_t*)(ws + CHUNK_OFF + (size_t)C * 524288ull);

    // zero r0acc + sxacc (16384 floats) -- graph-capturable async memset.
    hipMemsetAsync(r0acc, 0, 16384 * sizeof(float), stream);

    for (int b0 = 0; b0 < NB; b0 += C) {
        const int cb = (NB - b0 < C) ? (NB - b0) : C;
        k_cvt_xst<<<dim3(8, 8, cb), 256, 0, stream>>>(xs, xst, b0,
                                                      wkq, wkqT, wlast, wsum, sxacc);
        k_qd     <<<dim3(2, 8, cb),  512, 0, stream>>>(xst, wkqT, qdb);
        k_attn   <<<dim3(16, 4, cb), 256, 0, stream>>>(qdb, xst, wlast, r0acc, b0);
    }
    k_out<<<dim3(NB, 2), 256, 0, stream>>>(wpv, r0acc, sxacc, wsum, (float*)d_out);
}